// Round 19
// baseline (151.949 us; speedup 1.0000x reference)
//
#include <hip/hip_runtime.h>
#include <stdint.h>

#define NTOK 4096
#define HDIM 1024
#define DDIM 2048
#define NEXP 8
#define NASS 8192   // NTOK * K (K=2)

typedef __attribute__((ext_vector_type(8))) short bf16x8;
typedef __attribute__((ext_vector_type(4))) float f32x4;

typedef __attribute__((address_space(1))) const unsigned int gu32;
typedef __attribute__((address_space(3))) unsigned int lu32;

// barrier that is ALSO a compiler memory fence (raw builtin is not; R5 raced)
#define BARRIER() asm volatile("s_barrier" ::: "memory")
#define WAIT_VM0() asm volatile("s_waitcnt vmcnt(0)" ::: "memory")
#define WAIT_LGKM0() do { asm volatile("s_waitcnt lgkmcnt(0)" ::: "memory"); \
                          __builtin_amdgcn_sched_barrier(0); } while (0)

__device__ __forceinline__ void async16(void* lds, const void* g) {
  __builtin_amdgcn_global_load_lds((gu32*)(uintptr_t)g, (lu32*)(uintptr_t)lds, 16, 0, 0);
}

__device__ __forceinline__ unsigned short f2bf(float f) {
  unsigned int u = __float_as_uint(f);
  return (unsigned short)((u + 0x7fffu + ((u >> 16) & 1u)) >> 16);
}
__device__ __forceinline__ float bf2f(unsigned short u) {
  return __uint_as_float(((unsigned int)u) << 16);
}
__device__ __forceinline__ unsigned int pack2(float lo, float hi) {
  return (unsigned int)f2bf(lo) | ((unsigned int)f2bf(hi) << 16);
}

// R13-verified 128x128 transpose tile: 256B write segments (16 lanes share one
// output row); tolerated 4-way LDS read conflict (cheaper than scattered writes).
__device__ __forceinline__ void transpose128(const float* __restrict__ in,
                                             unsigned short* __restrict__ out,
                                             int R, int C, int e, int bk, int bn,
                                             float* tile, int tid) {
  const size_t mbase = (size_t)e * R * C;
#pragma unroll
  for (int it = 0; it < 16; ++it) {
    int row = it * 8 + (tid >> 5);
    int c4 = (tid & 31) * 4;
    float4 v = *reinterpret_cast<const float4*>(
        in + mbase + (size_t)(bk * 128 + row) * C + bn * 128 + c4);
    tile[row * 129 + c4 + 0] = v.x; tile[row * 129 + c4 + 1] = v.y;
    tile[row * 129 + c4 + 2] = v.z; tile[row * 129 + c4 + 3] = v.w;
  }
  __syncthreads();
#pragma unroll
  for (int it = 0; it < 8; ++it) {
    int n = it * 16 + (tid >> 4);
    int k8 = (tid & 15) * 8;
    uint4 o;
    o.x = pack2(tile[(k8 + 0) * 129 + n], tile[(k8 + 1) * 129 + n]);
    o.y = pack2(tile[(k8 + 2) * 129 + n], tile[(k8 + 3) * 129 + n]);
    o.z = pack2(tile[(k8 + 4) * 129 + n], tile[(k8 + 5) * 129 + n]);
    o.w = pack2(tile[(k8 + 6) * 129 + n], tile[(k8 + 7) * 129 + n]);
    *reinterpret_cast<uint4*>(out + mbase + (size_t)(bn * 128 + n) * R + bk * 128 + k8) = o;
  }
}

// ---------------- prep: route(block 0) + dn-transpose + cvt_x ----------------
// up-transpose moved into k_gemm_down's head blocks (dispatch-first overlap, the
// mechanism validated by R18's route-at-block-0: first-dispatched roles hide under
// the bulk work; last-dispatched ones serialize as a tail).
__global__ __launch_bounds__(256) void k_prep(
    const float* __restrict__ x, unsigned short* __restrict__ x16,
    const float* __restrict__ dn, unsigned short* __restrict__ dnT,
    const int* __restrict__ idx, const float* __restrict__ ew,
    const int* __restrict__ amask,
    int* __restrict__ counts_g, int* __restrict__ offs_g,
    int* __restrict__ toks, float* __restrict__ wl, int* __restrict__ slotmap) {
  __shared__ float tile[128 * 129];
  const int b = blockIdx.x;
  const int tid = threadIdx.x;
  if (b == 0) {
    // routing role (dispatched first -> overlaps the memory-bound blocks)
    int* ishm = (int*)tile;   // [0..7]=cnt, [8..15]=cur, [16]=flag
    if (tid < NEXP) ishm[tid] = 0;
    if (tid == 8) ishm[16] = 0;
    __syncthreads();
    int lf = 0;
#pragma unroll
    for (int j = 0; j < 16; ++j) {
      int i = tid + j * 256;             // tokens 0..4095 (high words)
      if (idx[2 * i + 1] != 0) lf = 1;   // int64 high words all 0 if int64
    }
    if (lf) atomicOr(&ishm[16], 1);
    __syncthreads();
    const int is32 = ishm[16];
    int e[32];
#pragma unroll
    for (int j = 0; j < 32; ++j) {
      int i = tid + j * 256;
      int ei = is32 ? idx[i] : idx[2 * i];
      e[j] = ei;
      atomicAdd(&ishm[ei], 1);
    }
    __syncthreads();
    if (tid == 0) {
      int off = 0;
      for (int k = 0; k < NEXP; ++k) {
        ishm[8 + k] = off; offs_g[k] = off; counts_g[k] = ishm[k]; off += ishm[k];
      }
    }
    __syncthreads();
#pragma unroll
    for (int j = 0; j < 32; ++j) {
      int i = tid + j * 256;
      int n = i >> 1;
      int slot = atomicAdd(&ishm[8 + e[j]], 1);
      toks[slot] = n;
      wl[slot] = ew[i] * (amask[n] ? 1.0f : 0.0f);
      slotmap[i] = slot;
    }
  } else if (b < 1025) {
    // dn: [E][1024][2048] -> dnT [E][2048][1024]; 8x16 tiles of 128 per expert
    int i2 = b - 1;
    int e = i2 >> 7, t = i2 & 127;
    transpose128(dn, dnT, HDIM, DDIM, e, t & 7, t >> 3, tile, tid);
  } else {
    // x fp32 -> bf16, 8 elems/thread (16B stores)
    int i = (b - 1025) * 2048 + tid * 8;
    float4 v0 = *reinterpret_cast<const float4*>(x + i);
    float4 v1 = *reinterpret_cast<const float4*>(x + i + 4);
    uint4 o;
    o.x = pack2(v0.x, v0.y); o.y = pack2(v0.z, v0.w);
    o.z = pack2(v1.x, v1.y); o.w = pack2(v1.z, v1.w);
    *reinterpret_cast<uint4*>(x16 + i) = o;
  }
}

// ---------------- grouped GEMM1 + up-transpose head ----------------
// y<128: up-transpose role (dispatched FIRST, overlaps GEMM; expert e = blockIdx.x
// so upT[e] is produced on XCD e -> L2-local for k_gemm_up).
// y>=128: 128x128 GEMM tile, BK=64, 256 thr / 4 waves, per-wave 64x64 (acc[4][4]),
// 64KB LDS dbuf, single barrier + single vmcnt(0) per K-tile (race-free since R6).
__global__ __launch_bounds__(256, 2) void k_gemm_down(
    const unsigned short* __restrict__ x16, const unsigned short* __restrict__ bT,
    const float* __restrict__ up, unsigned short* __restrict__ upT,
    const int* __restrict__ counts, const int* __restrict__ offs,
    const int* __restrict__ toks, unsigned short* __restrict__ hid) {
  __shared__ float tilef[128 * 129];       // 66048B union: transpose fp32 tile / GEMM dbuf
  const int e = blockIdx.x;                // expert == XCD
  const int tid = threadIdx.x;
  if (blockIdx.y < 128) {
    // up: [E][2048][1024] -> upT [E][1024][2048]; 16x8 tiles of 128 per expert
    int t = blockIdx.y;
    transpose128(up, upT, DDIM, HDIM, e, t & 15, t >> 4, tilef, tid);
    return;
  }
  const int cnt = counts[e];
  const int q = blockIdx.y - 128;
  const int mt = q >> 4;                    // 0..63
  const int nt = q & 15;                    // 0..15 (DDIM/128)
  if (mt * 128 >= cnt) return;
  const int base = offs[e];
  char* lds = (char*)tilef;                 // A: 2x16KB @0, B: 2x16KB @32768
  const int lane = tid & 63;
  const int wr = ((tid >> 7) & 1) * 64;     // wave M block (2)
  const int wc = ((tid >> 6) & 1) * 64;     // wave N block (2)

  const char* gA[4]; const char* gB[4]; int sOff[4];
  {
    const int swcol = ((tid & 7) << 4) ^ (((tid >> 3) & 7) << 4);
#pragma unroll
    for (int s = 0; s < 4; ++s) {
      int row = s * 32 + (tid >> 3);
      int sl = mt * 128 + row; if (sl >= cnt) sl = cnt - 1;
      gA[s] = (const char*)(x16 + (size_t)toks[base + sl] * HDIM) + swcol;
      gB[s] = (const char*)(bT + (size_t)e * DDIM * HDIM + (size_t)(nt * 128 + row) * HDIM) + swcol;
      sOff[s] = s * 4096 + tid * 16;
    }
  }
  const int swz = (lane & 7) << 4;
  const int lo = (lane >> 4) << 4;
  int rowA[4], rowB[4];
#pragma unroll
  for (int m = 0; m < 4; ++m) rowA[m] = (wr + m * 16 + (lane & 15)) * 128;
#pragma unroll
  for (int n = 0; n < 4; ++n) rowB[n] = (wc + n * 16 + (lane & 15)) * 128;

#pragma unroll
  for (int s = 0; s < 4; ++s) {
    async16(lds + sOff[s], gA[s]);
    async16(lds + 32768 + sOff[s], gB[s]);
  }

  f32x4 acc[4][4] = {};
  for (int j = 0; j < 16; ++j) {
    WAIT_VM0();
    BARRIER();
    char* curA = lds + ((j & 1) << 14);
    char* curB = lds + 32768 + ((j & 1) << 14);
    if (j < 15) {
      const int ko = (j + 1) << 7;
      char* nA = lds + ((~j & 1) << 14);
      char* nB = lds + 32768 + ((~j & 1) << 14);
#pragma unroll
      for (int s = 0; s < 4; ++s) {
        async16(nA + sOff[s], gA[s] + ko);
        async16(nB + sOff[s], gB[s] + ko);
      }
    }
#pragma unroll
    for (int ks = 0; ks < 2; ++ks) {
      const int cx = ((ks << 6) | lo) ^ swz;
      bf16x8 fa[4], fb[4];
#pragma unroll
      for (int n = 0; n < 4; ++n) fb[n] = *reinterpret_cast<const bf16x8*>(curB + rowB[n] + cx);
#pragma unroll
      for (int m = 0; m < 4; ++m) fa[m] = *reinterpret_cast<const bf16x8*>(curA + rowA[m] + cx);
      WAIT_LGKM0();
      __builtin_amdgcn_s_setprio(1);
#pragma unroll
      for (int m = 0; m < 4; ++m)
#pragma unroll
        for (int n = 0; n < 4; ++n)
          acc[m][n] = __builtin_amdgcn_mfma_f32_16x16x32_bf16(fa[m], fb[n], acc[m][n], 0, 0, 0);
      __builtin_amdgcn_s_setprio(0);
    }
  }

#pragma unroll
  for (int m = 0; m < 4; ++m) {
    int r0 = mt * 128 + wr + m * 16 + ((lane >> 4) * 4);
#pragma unroll
    for (int jj = 0; jj < 4; ++jj) {
      int r = r0 + jj;
      if (r < cnt) {
        unsigned short* dst = hid + (size_t)(base + r) * DDIM + nt * 128 + wc + (lane & 15);
#pragma unroll
        for (int n = 0; n < 4; ++n) {
          float v = acc[m][n][jj];
          dst[n * 16] = f2bf(v > 0.f ? v : 0.f);
        }
      }
    }
  }
}

// ---------------- grouped GEMM2: yw[slot] = hid[slot] @ up  (K=2048) ----------------
__global__ __launch_bounds__(256, 4) void k_gemm_up(
    const unsigned short* __restrict__ hid, const unsigned short* __restrict__ bT,
    const int* __restrict__ counts, const int* __restrict__ offs,
    unsigned short* __restrict__ yw) {
  const int e = blockIdx.x;                 // expert == XCD
  const int cnt = counts[e];
  const int q = blockIdx.y;
  const int mt = q >> 3;                    // 0..63
  const int nt = q & 7;                     // 0..7 (HDIM/128)
  if (mt * 128 >= cnt) return;
  const int base = offs[e];
  __shared__ alignas(16) char lds[65536];
  const int tid = threadIdx.x;
  const int lane = tid & 63;
  const int wr = ((tid >> 7) & 1) * 64;
  const int wc = ((tid >> 6) & 1) * 64;

  const char* gA[4]; const char* gB[4]; int sOff[4];
  {
    const int swcol = ((tid & 7) << 4) ^ (((tid >> 3) & 7) << 4);
#pragma unroll
    for (int s = 0; s < 4; ++s) {
      int row = s * 32 + (tid >> 3);
      int sl = mt * 128 + row; if (sl >= cnt) sl = cnt - 1;
      gA[s] = (const char*)(hid + (size_t)(base + sl) * DDIM) + swcol;
      gB[s] = (const char*)(bT + (size_t)e * HDIM * DDIM + (size_t)(nt * 128 + row) * DDIM) + swcol;
      sOff[s] = s * 4096 + tid * 16;
    }
  }
  const int swz = (lane & 7) << 4;
  const int lo = (lane >> 4) << 4;
  int rowA[4], rowB[4];
#pragma unroll
  for (int m = 0; m < 4; ++m) rowA[m] = (wr + m * 16 + (lane & 15)) * 128;
#pragma unroll
  for (int n = 0; n < 4; ++n) rowB[n] = (wc + n * 16 + (lane & 15)) * 128;

#pragma unroll
  for (int s = 0; s < 4; ++s) {
    async16(lds + sOff[s], gA[s]);
    async16(lds + 32768 + sOff[s], gB[s]);
  }

  f32x4 acc[4][4] = {};
  for (int j = 0; j < 32; ++j) {
    WAIT_VM0();
    BARRIER();
    char* curA = lds + ((j & 1) << 14);
    char* curB = lds + 32768 + ((j & 1) << 14);
    if (j < 31) {
      const int ko = (j + 1) << 7;
      char* nA = lds + ((~j & 1) << 14);
      char* nB = lds + 32768 + ((~j & 1) << 14);
#pragma unroll
      for (int s = 0; s < 4; ++s) {
        async16(nA + sOff[s], gA[s] + ko);
        async16(nB + sOff[s], gB[s] + ko);
      }
    }
#pragma unroll
    for (int ks = 0; ks < 2; ++ks) {
      const int cx = ((ks << 6) | lo) ^ swz;
      bf16x8 fa[4], fb[4];
#pragma unroll
      for (int n = 0; n < 4; ++n) fb[n] = *reinterpret_cast<const bf16x8*>(curB + rowB[n] + cx);
#pragma unroll
      for (int m = 0; m < 4; ++m) fa[m] = *reinterpret_cast<const bf16x8*>(curA + rowA[m] + cx);
      WAIT_LGKM0();
      __builtin_amdgcn_s_setprio(1);
#pragma unroll
      for (int m = 0; m < 4; ++m)
#pragma unroll
        for (int n = 0; n < 4; ++n)
          acc[m][n] = __builtin_amdgcn_mfma_f32_16x16x32_bf16(fa[m], fb[n], acc[m][n], 0, 0, 0);
      __builtin_amdgcn_s_setprio(0);
    }
  }

#pragma unroll
  for (int m = 0; m < 4; ++m) {
    int r0 = mt * 128 + wr + m * 16 + ((lane >> 4) * 4);
#pragma unroll
    for (int jj = 0; jj < 4; ++jj) {
      int r = r0 + jj;
      if (r < cnt) {
        unsigned short* dst = yw + (size_t)(base + r) * HDIM + nt * 128 + wc + (lane & 15);
#pragma unroll
        for (int n = 0; n < 4; ++n) dst[n * 16] = f2bf(acc[m][n][jj]);
      }
    }
  }
}

// ---------------- combine: out = x + w0*y0 + w1*y1 ----------------
__global__ __launch_bounds__(256) void k_combine(
    const float* __restrict__ x, const unsigned short* __restrict__ yw,
    const int* __restrict__ slotmap, const float* __restrict__ wl,
    float* __restrict__ out) {
  const int n = blockIdx.x;
  const int t = threadIdx.x;
  const int s0 = slotmap[2 * n], s1 = slotmap[2 * n + 1];
  const float w0 = wl[s0], w1 = wl[s1];
  float4 xv = reinterpret_cast<const float4*>(x + (size_t)n * HDIM)[t];
  ushort4 a0 = reinterpret_cast<const ushort4*>(yw + (size_t)s0 * HDIM)[t];
  ushort4 b0 = reinterpret_cast<const ushort4*>(yw + (size_t)s1 * HDIM)[t];
  float4 r;
  r.x = xv.x + w0 * bf2f(a0.x) + w1 * bf2f(b0.x);
  r.y = xv.y + w0 * bf2f(a0.y) + w1 * bf2f(b0.y);
  r.z = xv.z + w0 * bf2f(a0.z) + w1 * bf2f(b0.z);
  r.w = xv.w + w0 * bf2f(a0.w) + w1 * bf2f(b0.w);
  reinterpret_cast<float4*>(out + (size_t)n * HDIM)[t] = r;
}

extern "C" void kernel_launch(void* const* d_in, const int* in_sizes, int n_in,
                              void* d_out, int out_size, void* d_ws, size_t ws_size,
                              hipStream_t stream) {
  const float* x    = (const float*)d_in[0];
  const int* amask  = (const int*)d_in[1];
  const float* ew   = (const float*)d_in[2];
  const int* cidx   = (const int*)d_in[3];
  const float* dn   = (const float*)d_in[4];
  const float* up   = (const float*)d_in[5];
  float* out        = (float*)d_out;
  char* ws          = (char*)d_ws;

  const size_t X16_OFF = 0;
  const size_t DNT_OFF = X16_OFF + (size_t)NTOK * HDIM * 2;             // 8.4MB
  const size_t UPT_OFF = DNT_OFF + (size_t)NEXP * HDIM * DDIM * 2;      // +33.5MB
  const size_t HID_OFF = UPT_OFF + (size_t)NEXP * HDIM * DDIM * 2;      // +33.5MB
  const size_t MET_OFF = HID_OFF + (size_t)NASS * DDIM * 2;             // +33.5MB

  unsigned short* x16 = (unsigned short*)(ws + X16_OFF);
  unsigned short* dnT = (unsigned short*)(ws + DNT_OFF);
  unsigned short* upT = (unsigned short*)(ws + UPT_OFF);
  unsigned short* hid = (unsigned short*)(ws + HID_OFF);
  // yw ([NASS][HDIM] bf16, 16.8MB) aliases dnT: dnT dead after k_gemm_down
  unsigned short* yw  = (unsigned short*)(ws + DNT_OFF);
  int* counts  = (int*)(ws + MET_OFF);
  int* offs    = counts + 8;
  int* toks    = counts + 32;
  float* wl    = (float*)(toks + NASS);
  int* slotmap = (int*)(wl + NASS);

  // prep blocks: 0 = routing (first -> overlapped), [1,1025) dnT, [1025,3073) x-cvt
  k_prep<<<3073, 256, 0, stream>>>(x, x16, dn, dnT,
                                   cidx, ew, amask, counts, offs, toks, wl, slotmap);
  // blockIdx.x == XCD id (round-robin dispatch) == expert id.
  // y<128: up-transpose (dispatch-first overlap); y>=128: GEMM tiles.
  k_gemm_down<<<dim3(8, 128 + 1024), 256, 0, stream>>>(x16, dnT, up, upT,
                                                       counts, offs, toks, hid);
  k_gemm_up<<<dim3(8, 512), 256, 0, stream>>>(hid, upT, counts, offs, yw);
  k_combine<<<NTOK, 256, 0, stream>>>(x, yw, slotmap, wl, out);
}

// Round 20
// 145.637 us; speedup vs baseline: 1.0433x; 1.0433x over previous
//
#include <hip/hip_runtime.h>
#include <stdint.h>

#define NTOK 4096
#define HDIM 1024
#define DDIM 2048
#define NEXP 8
#define NASS 8192   // NTOK * K (K=2)

typedef __attribute__((ext_vector_type(8))) short bf16x8;
typedef __attribute__((ext_vector_type(4))) float f32x4;

typedef __attribute__((address_space(1))) const unsigned int gu32;
typedef __attribute__((address_space(3))) unsigned int lu32;

// barrier that is ALSO a compiler memory fence (raw builtin is not; R5 raced)
#define BARRIER() asm volatile("s_barrier" ::: "memory")
#define WAIT_VM0() asm volatile("s_waitcnt vmcnt(0)" ::: "memory")
#define WAIT_LGKM0() do { asm volatile("s_waitcnt lgkmcnt(0)" ::: "memory"); \
                          __builtin_amdgcn_sched_barrier(0); } while (0)

__device__ __forceinline__ void async16(void* lds, const void* g) {
  __builtin_amdgcn_global_load_lds((gu32*)(uintptr_t)g, (lu32*)(uintptr_t)lds, 16, 0, 0);
}

__device__ __forceinline__ unsigned short f2bf(float f) {
  unsigned int u = __float_as_uint(f);
  return (unsigned short)((u + 0x7fffu + ((u >> 16) & 1u)) >> 16);
}
__device__ __forceinline__ float bf2f(unsigned short u) {
  return __uint_as_float(((unsigned int)u) << 16);
}
__device__ __forceinline__ unsigned int pack2(float lo, float hi) {
  return (unsigned int)f2bf(lo) | ((unsigned int)f2bf(hi) << 16);
}

// ---------------- prep: route(block 0, overlapped) + transposes + cvt_x ----------------
// R13-verified transpose: 256B write segments (16 lanes share one output row);
// carries a 4-way LDS read conflict (~3µs) — cheaper than scattered writes (R16: +19µs).
// Route at block 0 so it dispatches FIRST and hides under the transposes
// (at block 4096 it tailed the kernel: R16/R17 +13µs). Fusing the BULK transposes
// into the GEMM regresses (R8/R19): only small roles hide for free.
__device__ __forceinline__ void transpose128(const float* __restrict__ in,
                                             unsigned short* __restrict__ out,
                                             int R, int C, int e, int bk, int bn,
                                             float* tile, int tid) {
  const size_t mbase = (size_t)e * R * C;
#pragma unroll
  for (int it = 0; it < 16; ++it) {
    int row = it * 8 + (tid >> 5);
    int c4 = (tid & 31) * 4;
    float4 v = *reinterpret_cast<const float4*>(
        in + mbase + (size_t)(bk * 128 + row) * C + bn * 128 + c4);
    tile[row * 129 + c4 + 0] = v.x; tile[row * 129 + c4 + 1] = v.y;
    tile[row * 129 + c4 + 2] = v.z; tile[row * 129 + c4 + 3] = v.w;
  }
  __syncthreads();
#pragma unroll
  for (int it = 0; it < 8; ++it) {
    int n = it * 16 + (tid >> 4);
    int k8 = (tid & 15) * 8;
    uint4 o;
    o.x = pack2(tile[(k8 + 0) * 129 + n], tile[(k8 + 1) * 129 + n]);
    o.y = pack2(tile[(k8 + 2) * 129 + n], tile[(k8 + 3) * 129 + n]);
    o.z = pack2(tile[(k8 + 4) * 129 + n], tile[(k8 + 5) * 129 + n]);
    o.w = pack2(tile[(k8 + 6) * 129 + n], tile[(k8 + 7) * 129 + n]);
    *reinterpret_cast<uint4*>(out + mbase + (size_t)(bn * 128 + n) * R + bk * 128 + k8) = o;
  }
}

__global__ __launch_bounds__(256) void k_prep(
    const float* __restrict__ x, unsigned short* __restrict__ x16,
    const float* __restrict__ dn, unsigned short* __restrict__ dnT,
    const float* __restrict__ up, unsigned short* __restrict__ upT,
    const int* __restrict__ idx, const float* __restrict__ ew,
    const int* __restrict__ amask,
    int* __restrict__ counts_g, int* __restrict__ offs_g,
    int* __restrict__ toks, float* __restrict__ wl, int* __restrict__ slotmap) {
  __shared__ float tile[128 * 129];
  const int b = blockIdx.x;
  const int tid = threadIdx.x;
  if (b == 0) {
    // routing role (dispatched first -> overlaps the memory-bound blocks)
    int* ishm = (int*)tile;   // [0..7]=cnt, [8..15]=cur, [16]=flag
    if (tid < NEXP) ishm[tid] = 0;
    if (tid == 8) ishm[16] = 0;
    __syncthreads();
    int lf = 0;
#pragma unroll
    for (int j = 0; j < 16; ++j) {
      int i = tid + j * 256;             // tokens 0..4095 (high words)
      if (idx[2 * i + 1] != 0) lf = 1;   // int64 high words all 0 if int64
    }
    if (lf) atomicOr(&ishm[16], 1);
    __syncthreads();
    const int is32 = ishm[16];
    int e[32];
#pragma unroll
    for (int j = 0; j < 32; ++j) {
      int i = tid + j * 256;
      int ei = is32 ? idx[i] : idx[2 * i];
      e[j] = ei;
      atomicAdd(&ishm[ei], 1);
    }
    __syncthreads();
    if (tid == 0) {
      int off = 0;
      for (int k = 0; k < NEXP; ++k) {
        ishm[8 + k] = off; offs_g[k] = off; counts_g[k] = ishm[k]; off += ishm[k];
      }
    }
    __syncthreads();
#pragma unroll
    for (int j = 0; j < 32; ++j) {
      int i = tid + j * 256;
      int n = i >> 1;
      int slot = atomicAdd(&ishm[8 + e[j]], 1);
      toks[slot] = n;
      wl[slot] = ew[i] * (amask[n] ? 1.0f : 0.0f);
      slotmap[i] = slot;
    }
  } else if (b < 1025) {
    // dn: [E][1024][2048] -> dnT [E][2048][1024]; 8x16 tiles of 128 per expert
    int i2 = b - 1;
    int e = i2 >> 7, t = i2 & 127;
    transpose128(dn, dnT, HDIM, DDIM, e, t & 7, t >> 3, tile, tid);
  } else if (b < 2049) {
    // up: [E][2048][1024] -> upT [E][1024][2048]; 16x8 tiles of 128 per expert
    int i2 = b - 1025;
    int e = i2 >> 7, t = i2 & 127;
    transpose128(up, upT, DDIM, HDIM, e, t & 15, t >> 4, tile, tid);
  } else {
    // x fp32 -> bf16, 8 elems/thread (16B stores)
    int i = (b - 2049) * 2048 + tid * 8;
    float4 v0 = *reinterpret_cast<const float4*>(x + i);
    float4 v1 = *reinterpret_cast<const float4*>(x + i + 4);
    uint4 o;
    o.x = pack2(v0.x, v0.y); o.y = pack2(v0.z, v0.w);
    o.z = pack2(v1.x, v1.y); o.w = pack2(v1.z, v1.w);
    *reinterpret_cast<uint4*>(x16 + i) = o;
  }
}

// ---------------- grouped GEMM1: hid = relu(X[gather] @ down) ----------------
// 128x128 tile, BK=64, 256 thr / 4 waves (2Mx2N), per-wave 64x64 (acc[4][4]):
// 2.0 MFMA per ds_read_b128, 64KB LDS dbuf -> 2 blocks/CU.
// Single barrier + single vmcnt(0) per K-tile (race-free since R6).
// Expert->XCD colocation: blockIdx.x == XCD == expert.
__global__ __launch_bounds__(256, 4) void k_gemm_down(
    const unsigned short* __restrict__ x16, const unsigned short* __restrict__ bT,
    const int* __restrict__ counts, const int* __restrict__ offs,
    const int* __restrict__ toks, unsigned short* __restrict__ hid) {
  const int e = blockIdx.x;                 // expert == XCD
  const int cnt = counts[e];
  const int q = blockIdx.y;
  const int mt = q >> 4;                    // 0..63
  const int nt = q & 15;                    // 0..15 (DDIM/128)
  if (mt * 128 >= cnt) return;
  const int base = offs[e];
  __shared__ alignas(16) char lds[65536];   // A: 2x16KB @0, B: 2x16KB @32768
  const int tid = threadIdx.x;
  const int lane = tid & 63;
  const int wr = ((tid >> 7) & 1) * 64;     // wave M block (2)
  const int wc = ((tid >> 6) & 1) * 64;     // wave N block (2)

  const char* gA[4]; const char* gB[4]; int sOff[4];
  {
    const int swcol = ((tid & 7) << 4) ^ (((tid >> 3) & 7) << 4);
#pragma unroll
    for (int s = 0; s < 4; ++s) {
      int row = s * 32 + (tid >> 3);
      int sl = mt * 128 + row; if (sl >= cnt) sl = cnt - 1;
      gA[s] = (const char*)(x16 + (size_t)toks[base + sl] * HDIM) + swcol;
      gB[s] = (const char*)(bT + (size_t)e * DDIM * HDIM + (size_t)(nt * 128 + row) * HDIM) + swcol;
      sOff[s] = s * 4096 + tid * 16;
    }
  }
  const int swz = (lane & 7) << 4;
  const int lo = (lane >> 4) << 4;
  int rowA[4], rowB[4];
#pragma unroll
  for (int m = 0; m < 4; ++m) rowA[m] = (wr + m * 16 + (lane & 15)) * 128;
#pragma unroll
  for (int n = 0; n < 4; ++n) rowB[n] = (wc + n * 16 + (lane & 15)) * 128;

#pragma unroll
  for (int s = 0; s < 4; ++s) {
    async16(lds + sOff[s], gA[s]);
    async16(lds + 32768 + sOff[s], gB[s]);
  }

  f32x4 acc[4][4] = {};
  for (int j = 0; j < 16; ++j) {
    WAIT_VM0();
    BARRIER();
    char* curA = lds + ((j & 1) << 14);
    char* curB = lds + 32768 + ((j & 1) << 14);
    if (j < 15) {
      const int ko = (j + 1) << 7;
      char* nA = lds + ((~j & 1) << 14);
      char* nB = lds + 32768 + ((~j & 1) << 14);
#pragma unroll
      for (int s = 0; s < 4; ++s) {
        async16(nA + sOff[s], gA[s] + ko);
        async16(nB + sOff[s], gB[s] + ko);
      }
    }
#pragma unroll
    for (int ks = 0; ks < 2; ++ks) {
      const int cx = ((ks << 6) | lo) ^ swz;
      bf16x8 fa[4], fb[4];
#pragma unroll
      for (int n = 0; n < 4; ++n) fb[n] = *reinterpret_cast<const bf16x8*>(curB + rowB[n] + cx);
#pragma unroll
      for (int m = 0; m < 4; ++m) fa[m] = *reinterpret_cast<const bf16x8*>(curA + rowA[m] + cx);
      WAIT_LGKM0();
      __builtin_amdgcn_s_setprio(1);
#pragma unroll
      for (int m = 0; m < 4; ++m)
#pragma unroll
        for (int n = 0; n < 4; ++n)
          acc[m][n] = __builtin_amdgcn_mfma_f32_16x16x32_bf16(fa[m], fb[n], acc[m][n], 0, 0, 0);
      __builtin_amdgcn_s_setprio(0);
    }
  }

#pragma unroll
  for (int m = 0; m < 4; ++m) {
    int r0 = mt * 128 + wr + m * 16 + ((lane >> 4) * 4);
#pragma unroll
    for (int jj = 0; jj < 4; ++jj) {
      int r = r0 + jj;
      if (r < cnt) {
        unsigned short* dst = hid + (size_t)(base + r) * DDIM + nt * 128 + wc + (lane & 15);
#pragma unroll
        for (int n = 0; n < 4; ++n) {
          float v = acc[m][n][jj];
          dst[n * 16] = f2bf(v > 0.f ? v : 0.f);
        }
      }
    }
  }
}

// ---------------- grouped GEMM2: yw[slot] = hid[slot] @ up  (K=2048) ----------------
__global__ __launch_bounds__(256, 4) void k_gemm_up(
    const unsigned short* __restrict__ hid, const unsigned short* __restrict__ bT,
    const int* __restrict__ counts, const int* __restrict__ offs,
    unsigned short* __restrict__ yw) {
  const int e = blockIdx.x;                 // expert == XCD
  const int cnt = counts[e];
  const int q = blockIdx.y;
  const int mt = q >> 3;                    // 0..63
  const int nt = q & 7;                     // 0..7 (HDIM/128)
  if (mt * 128 >= cnt) return;
  const int base = offs[e];
  __shared__ alignas(16) char lds[65536];
  const int tid = threadIdx.x;
  const int lane = tid & 63;
  const int wr = ((tid >> 7) & 1) * 64;
  const int wc = ((tid >> 6) & 1) * 64;

  const char* gA[4]; const char* gB[4]; int sOff[4];
  {
    const int swcol = ((tid & 7) << 4) ^ (((tid >> 3) & 7) << 4);
#pragma unroll
    for (int s = 0; s < 4; ++s) {
      int row = s * 32 + (tid >> 3);
      int sl = mt * 128 + row; if (sl >= cnt) sl = cnt - 1;
      gA[s] = (const char*)(hid + (size_t)(base + sl) * DDIM) + swcol;
      gB[s] = (const char*)(bT + (size_t)e * HDIM * DDIM + (size_t)(nt * 128 + row) * DDIM) + swcol;
      sOff[s] = s * 4096 + tid * 16;
    }
  }
  const int swz = (lane & 7) << 4;
  const int lo = (lane >> 4) << 4;
  int rowA[4], rowB[4];
#pragma unroll
  for (int m = 0; m < 4; ++m) rowA[m] = (wr + m * 16 + (lane & 15)) * 128;
#pragma unroll
  for (int n = 0; n < 4; ++n) rowB[n] = (wc + n * 16 + (lane & 15)) * 128;

#pragma unroll
  for (int s = 0; s < 4; ++s) {
    async16(lds + sOff[s], gA[s]);
    async16(lds + 32768 + sOff[s], gB[s]);
  }

  f32x4 acc[4][4] = {};
  for (int j = 0; j < 32; ++j) {
    WAIT_VM0();
    BARRIER();
    char* curA = lds + ((j & 1) << 14);
    char* curB = lds + 32768 + ((j & 1) << 14);
    if (j < 31) {
      const int ko = (j + 1) << 7;
      char* nA = lds + ((~j & 1) << 14);
      char* nB = lds + 32768 + ((~j & 1) << 14);
#pragma unroll
      for (int s = 0; s < 4; ++s) {
        async16(nA + sOff[s], gA[s] + ko);
        async16(nB + sOff[s], gB[s] + ko);
      }
    }
#pragma unroll
    for (int ks = 0; ks < 2; ++ks) {
      const int cx = ((ks << 6) | lo) ^ swz;
      bf16x8 fa[4], fb[4];
#pragma unroll
      for (int n = 0; n < 4; ++n) fb[n] = *reinterpret_cast<const bf16x8*>(curB + rowB[n] + cx);
#pragma unroll
      for (int m = 0; m < 4; ++m) fa[m] = *reinterpret_cast<const bf16x8*>(curA + rowA[m] + cx);
      WAIT_LGKM0();
      __builtin_amdgcn_s_setprio(1);
#pragma unroll
      for (int m = 0; m < 4; ++m)
#pragma unroll
        for (int n = 0; n < 4; ++n)
          acc[m][n] = __builtin_amdgcn_mfma_f32_16x16x32_bf16(fa[m], fb[n], acc[m][n], 0, 0, 0);
      __builtin_amdgcn_s_setprio(0);
    }
  }

#pragma unroll
  for (int m = 0; m < 4; ++m) {
    int r0 = mt * 128 + wr + m * 16 + ((lane >> 4) * 4);
#pragma unroll
    for (int jj = 0; jj < 4; ++jj) {
      int r = r0 + jj;
      if (r < cnt) {
        unsigned short* dst = yw + (size_t)(base + r) * HDIM + nt * 128 + wc + (lane & 15);
#pragma unroll
        for (int n = 0; n < 4; ++n) dst[n * 16] = f2bf(acc[m][n][jj]);
      }
    }
  }
}

// ---------------- combine: out = x + w0*y0 + w1*y1 ----------------
__global__ __launch_bounds__(256) void k_combine(
    const float* __restrict__ x, const unsigned short* __restrict__ yw,
    const int* __restrict__ slotmap, const float* __restrict__ wl,
    float* __restrict__ out) {
  const int n = blockIdx.x;
  const int t = threadIdx.x;
  const int s0 = slotmap[2 * n], s1 = slotmap[2 * n + 1];
  const float w0 = wl[s0], w1 = wl[s1];
  float4 xv = reinterpret_cast<const float4*>(x + (size_t)n * HDIM)[t];
  ushort4 a0 = reinterpret_cast<const ushort4*>(yw + (size_t)s0 * HDIM)[t];
  ushort4 b0 = reinterpret_cast<const ushort4*>(yw + (size_t)s1 * HDIM)[t];
  float4 r;
  r.x = xv.x + w0 * bf2f(a0.x) + w1 * bf2f(b0.x);
  r.y = xv.y + w0 * bf2f(a0.y) + w1 * bf2f(b0.y);
  r.z = xv.z + w0 * bf2f(a0.z) + w1 * bf2f(b0.z);
  r.w = xv.w + w0 * bf2f(a0.w) + w1 * bf2f(b0.w);
  reinterpret_cast<float4*>(out + (size_t)n * HDIM)[t] = r;
}

extern "C" void kernel_launch(void* const* d_in, const int* in_sizes, int n_in,
                              void* d_out, int out_size, void* d_ws, size_t ws_size,
                              hipStream_t stream) {
  const float* x    = (const float*)d_in[0];
  const int* amask  = (const int*)d_in[1];
  const float* ew   = (const float*)d_in[2];
  const int* cidx   = (const int*)d_in[3];
  const float* dn   = (const float*)d_in[4];
  const float* up   = (const float*)d_in[5];
  float* out        = (float*)d_out;
  char* ws          = (char*)d_ws;

  const size_t X16_OFF = 0;
  const size_t DNT_OFF = X16_OFF + (size_t)NTOK * HDIM * 2;             // 8.4MB
  const size_t UPT_OFF = DNT_OFF + (size_t)NEXP * HDIM * DDIM * 2;      // +33.5MB
  const size_t HID_OFF = UPT_OFF + (size_t)NEXP * HDIM * DDIM * 2;      // +33.5MB
  const size_t MET_OFF = HID_OFF + (size_t)NASS * DDIM * 2;             // +33.5MB

  unsigned short* x16 = (unsigned short*)(ws + X16_OFF);
  unsigned short* dnT = (unsigned short*)(ws + DNT_OFF);
  unsigned short* upT = (unsigned short*)(ws + UPT_OFF);
  unsigned short* hid = (unsigned short*)(ws + HID_OFF);
  // yw ([NASS][HDIM] bf16, 16.8MB) aliases dnT: dnT dead after k_gemm_down
  unsigned short* yw  = (unsigned short*)(ws + DNT_OFF);
  int* counts  = (int*)(ws + MET_OFF);
  int* offs    = counts + 8;
  int* toks    = counts + 32;
  float* wl    = (float*)(toks + NASS);
  int* slotmap = (int*)(wl + NASS);

  // blocks: 0 = routing (first -> overlapped), [1,1025) dnT, [1025,2049) upT,
  // [2049,4097) x-cvt
  k_prep<<<4097, 256, 0, stream>>>(x, x16, dn, dnT, up, upT,
                                   cidx, ew, amask, counts, offs, toks, wl, slotmap);
  // blockIdx.x == XCD id (round-robin dispatch) == expert id
  k_gemm_down<<<dim3(8, 1024), 256, 0, stream>>>(x16, dnT, counts, offs, toks, hid);
  k_gemm_up<<<dim3(8, 512), 256, 0, stream>>>(hid, upT, counts, offs, yw);
  k_combine<<<NTOK, 256, 0, stream>>>(x, yw, slotmap, wl, out);
}